// Round 3
// baseline (79.323 us; speedup 1.0000x reference)
//
#include <hip/hip_runtime.h>

// Problem: B=4, L=256, D=768, OUT=256
//   pj[b,j,o] = sum_d text[b,j,d] * weight[o, d]
//   pi[b,i,o] = sum_d text[b,i,d] * weight[o, 768+d]
//   out[b,i,j,o] = pi[b,i,o] + pj[b,j,o] + bias[o]
// out: 4*256*256*256 f32 = 268 MB -> write-BW bound (~40 us floor at fill's 6.7-6.9 TB/s).
//
// ws layout (floats):
//   WT  [768][512]      : WT[d][h*256+o] = weight[o][h*768+d]   (393216 floats)
//   P   [2][1024][256]  : P[0]=pj, P[1]=pi+bias                 (524288 floats)

#define DDIM 768
#define WT_FLOATS (768 * 512)
#define P_HALF (1024 * 256)

typedef float f4 __attribute__((ext_vector_type(4)));

// ---- tiled weight transpose: weight[256][1536] -> WT[768][512] ----
__global__ __launch_bounds__(256) void k_transpose(const float* __restrict__ W,
                                                   float* __restrict__ WT) {
    __shared__ float t[32][33];
    const int c0 = blockIdx.x * 32;   // 0..1535 (48 tiles; 768%32==0, no straddle)
    const int o0 = blockIdx.y * 32;   // 0..255  (8 tiles)
    const int tx = threadIdx.x & 31, ty = threadIdx.x >> 5;
#pragma unroll
    for (int yy = ty; yy < 32; yy += 8)
        t[yy][tx] = W[(size_t)(o0 + yy) * 1536 + c0 + tx];
    __syncthreads();
#pragma unroll
    for (int yy = ty; yy < 32; yy += 8) {
        int c = c0 + yy;
        int h = (c >= 768) ? 1 : 0;
        int d = c - h * 768;
        WT[(size_t)d * 512 + h * 256 + o0 + tx] = t[tx][yy];
    }
}

// ---- P computation: 8 rows/block, 4-way d-split, 1024 threads ----
// grid (128, 2): x = row tile (m0 = 8*bx over B*L=1024 rows), y = half h
// thread: o = tid&255, dg = tid>>8 handles d in [dg*192, dg*192+192)
__global__ __launch_bounds__(1024) void k_gemv(const float* __restrict__ text,
                                               const float* __restrict__ bias,
                                               const float* __restrict__ WT,
                                               float* __restrict__ P) {
    __shared__ float red[4][8][256];   // 32 KB
    const int m0 = blockIdx.x * 8;
    const int h  = blockIdx.y;
    const int o  = threadIdx.x & 255;
    const int dg = __builtin_amdgcn_readfirstlane(threadIdx.x >> 8); // wave-uniform
    float acc[8];
#pragma unroll
    for (int r = 0; r < 8; ++r) acc[r] = 0.0f;
    const float* t0 = text + (size_t)m0 * DDIM + dg * 192;   // block+wave-uniform rows
    const float* wt = WT + (size_t)(dg * 192) * 512 + h * 256 + o;
#pragma unroll 8
    for (int d = 0; d < 192; ++d) {
        float w = wt[(size_t)d * 512];                       // coalesced across o, L2-hit
#pragma unroll
        for (int r = 0; r < 8; ++r)
            acc[r] = fmaf(t0[(size_t)r * DDIM + d], w, acc[r]);  // scalar (uniform)
    }
#pragma unroll
    for (int r = 0; r < 8; ++r) red[dg][r][o] = acc[r];
    __syncthreads();
    // 2048 outputs (8 r x 256 o), 1024 threads -> 2 each
#pragma unroll
    for (int k = 0; k < 2; ++k) {
        int flat = k * 1024 + threadIdx.x;
        int r = flat >> 8, oo = flat & 255;
        float s = red[0][r][oo] + red[1][r][oo] + red[2][r][oo] + red[3][r][oo];
        if (h) s += bias[oo];                                // fold bias into pi half
        P[(size_t)h * P_HALF + (size_t)(m0 + r) * 256 + oo] = s;
    }
}

// ---- register-tiled broadcast add ----
// block = 16 i-rows x 16 j-cols x 256 o. grid (64 i-tiles, 16 j-tiles).
// thread: o4 = (tid&63)*4, jg = tid>>6 owns 4 j's. Preload pj[4], pi[16]
// into registers, then 64 pure nontemporal f4 stores (write-stream like fill).
__global__ __launch_bounds__(256) void k_bcast(const float* __restrict__ P,
                                               float* __restrict__ out) {
    const int it = blockIdx.x;            // 0..63
    const int jt = blockIdx.y;            // 0..15
    const int b  = it >> 4;               // 16 i-tiles per batch
    const int o4 = (threadIdx.x & 63) * 4;
    const int jg = threadIdx.x >> 6;      // 0..3
    const int r0 = it * 16;
    const int j0 = jt * 16 + jg * 4;

    f4 pj4[4];
    const float* pjb = P + ((size_t)b * 256 + j0) * 256 + o4;
#pragma unroll
    for (int k = 0; k < 4; ++k) pj4[k] = *(const f4*)(pjb + k * 256);

    f4 pi4[16];
    const float* pib = P + P_HALF + (size_t)r0 * 256 + o4;
#pragma unroll
    for (int i = 0; i < 16; ++i) pi4[i] = *(const f4*)(pib + i * 256);

    float* outb = out + (size_t)r0 * 65536 + (size_t)j0 * 256 + o4;
#pragma unroll
    for (int i = 0; i < 16; ++i) {
        float* o_i = outb + (size_t)i * 65536;
#pragma unroll
        for (int k = 0; k < 4; ++k) {
            f4 v = pi4[i] + pj4[k];
            __builtin_nontemporal_store(v, (f4*)(o_i + k * 256));  // 1KB/wave contiguous
        }
    }
}

extern "C" void kernel_launch(void* const* d_in, const int* in_sizes, int n_in,
                              void* d_out, int out_size, void* d_ws, size_t ws_size,
                              hipStream_t stream) {
    const float* text   = (const float*)d_in[0];   // [4][256][768]
    const float* weight = (const float*)d_in[1];   // [256][1536]
    const float* bias   = (const float*)d_in[2];   // [256]
    float* out = (float*)d_out;                    // [4][256][256][256]
    float* WT  = (float*)d_ws;                     // [768][512]
    float* P   = WT + WT_FLOATS;                   // [2][1024][256]

    k_transpose<<<dim3(48, 8), 256, 0, stream>>>(weight, WT);
    k_gemv<<<dim3(128, 2), 1024, 0, stream>>>(text, bias, WT, P);
    k_bcast<<<dim3(64, 16), 256, 0, stream>>>(P, out);
}

// Round 4
// 69.822 us; speedup vs baseline: 1.1361x; 1.1361x over previous
//
#include <hip/hip_runtime.h>

// Problem: B=4, L=256, D=768, OUT=256
//   pj[b,j,o] = sum_d text[b,j,d] * weight[o, d]
//   pi[b,i,o] = sum_d text[b,i,d] * weight[o, 768+d]
//   out[b,i,j,o] = pi[b,i,o] + pj[b,j,o] + bias[o]
// out: 268 MB f32 -> write-BW bound (~40 us floor at fill's 6.7-6.9 TB/s).
//
// R4: bcast uses PLAIN stores (A/B vs nontemporal used R1-R3) + 2048 blocks
// for 32 waves/CU occupancy. gemv split to 512 blocks (2/CU).
//
// ws layout (floats):
//   WT  [768][512]      : WT[d][h*256+o] = weight[o][h*768+d]   (393216 floats)
//   P   [2][1024][256]  : P[0]=pj, P[1]=pi+bias                 (524288 floats)

#define DDIM 768
#define WT_FLOATS (768 * 512)
#define P_HALF (1024 * 256)

typedef float f4 __attribute__((ext_vector_type(4)));

// ---- tiled weight transpose: weight[256][1536] -> WT[768][512] ----
__global__ __launch_bounds__(256) void k_transpose(const float* __restrict__ W,
                                                   float* __restrict__ WT) {
    __shared__ float t[32][33];
    const int c0 = blockIdx.x * 32;   // 0..1535 (48 tiles; 768%32==0, no straddle)
    const int o0 = blockIdx.y * 32;   // 0..255  (8 tiles)
    const int tx = threadIdx.x & 31, ty = threadIdx.x >> 5;
#pragma unroll
    for (int yy = ty; yy < 32; yy += 8)
        t[yy][tx] = W[(size_t)(o0 + yy) * 1536 + c0 + tx];
    __syncthreads();
#pragma unroll
    for (int yy = ty; yy < 32; yy += 8) {
        int c = c0 + yy;
        int h = (c >= 768) ? 1 : 0;
        int d = c - h * 768;
        WT[(size_t)d * 512 + h * 256 + o0 + tx] = t[tx][yy];
    }
}

// ---- P computation: 4 rows/block, 4-way d-split, 1024 threads ----
// grid (256, 2): x = row tile (m0 = 4*bx over B*L=1024 rows), y = half h
// 512 blocks -> 2 blocks/CU -> 8 waves/SIMD for latency hiding.
__global__ __launch_bounds__(1024) void k_gemv(const float* __restrict__ text,
                                               const float* __restrict__ bias,
                                               const float* __restrict__ WT,
                                               float* __restrict__ P) {
    __shared__ float red[4][4][256];   // 16 KB
    const int m0 = blockIdx.x * 4;
    const int h  = blockIdx.y;
    const int o  = threadIdx.x & 255;
    const int dg = __builtin_amdgcn_readfirstlane(threadIdx.x >> 8); // wave-uniform
    float acc[4];
#pragma unroll
    for (int r = 0; r < 4; ++r) acc[r] = 0.0f;
    const float* t0 = text + (size_t)m0 * DDIM + dg * 192;   // block+wave-uniform rows
    const float* wt = WT + (size_t)(dg * 192) * 512 + h * 256 + o;
#pragma unroll 8
    for (int d = 0; d < 192; ++d) {
        float w = wt[(size_t)d * 512];                       // coalesced across o, L2-hit
#pragma unroll
        for (int r = 0; r < 4; ++r)
            acc[r] = fmaf(t0[(size_t)r * DDIM + d], w, acc[r]);  // uniform -> scalar
    }
#pragma unroll
    for (int r = 0; r < 4; ++r) red[dg][r][o] = acc[r];
    __syncthreads();
    // 1024 outputs (4 r x 256 o), 1024 threads -> 1 each
    {
        int r = threadIdx.x >> 8, oo = threadIdx.x & 255;
        float s = red[0][r][oo] + red[1][r][oo] + red[2][r][oo] + red[3][r][oo];
        if (h) s += bias[oo];                                // fold bias into pi half
        P[(size_t)h * P_HALF + (size_t)(m0 + r) * 256 + oo] = s;
    }
}

// ---- broadcast add: out[r][j][o] = pi[r][o] + pj[b*256+j][o] ----
// grid 2048: bid -> r = bid>>1 (0..1023), half = bid&1 (j in [128*half, 128*half+128))
// 256 threads: o4 = (tid&63)*4 fixed, jg = tid>>6, j steps by 4 (32 iters).
// PLAIN stores (A/B vs nontemporal).
__global__ __launch_bounds__(256) void k_bcast(const float* __restrict__ P,
                                               float* __restrict__ out) {
    const int bid  = blockIdx.x;
    const int r    = bid >> 1;
    const int half = bid & 1;
    const int b    = r >> 8;
    const int o4 = (threadIdx.x & 63) * 4;
    const int jg = threadIdx.x >> 6;
    const f4 pi4 = *(const f4*)(P + (size_t)P_HALF + (size_t)r * 256 + o4);
    const float* pjb = P + (size_t)b * 65536;        // pj[b*256 + j][o]
    float* outr = out + (size_t)r * 65536;
    const int j0 = half * 128 + jg;
#pragma unroll 8
    for (int j = j0; j < j0 + 128 - jg; j += 4) {
        f4 pj4 = *(const f4*)(pjb + j * 256 + o4);   // L2-resident
        f4 v = pi4 + pj4;
        *(f4*)(outr + j * 256 + o4) = v;             // plain store, 1KB/wave contiguous
    }
}

extern "C" void kernel_launch(void* const* d_in, const int* in_sizes, int n_in,
                              void* d_out, int out_size, void* d_ws, size_t ws_size,
                              hipStream_t stream) {
    const float* text   = (const float*)d_in[0];   // [4][256][768]
    const float* weight = (const float*)d_in[1];   // [256][1536]
    const float* bias   = (const float*)d_in[2];   // [256]
    float* out = (float*)d_out;                    // [4][256][256][256]
    float* WT  = (float*)d_ws;                     // [768][512]
    float* P   = WT + WT_FLOATS;                   // [2][1024][256]

    k_transpose<<<dim3(48, 8), 256, 0, stream>>>(weight, WT);
    k_gemv<<<dim3(256, 2), 1024, 0, stream>>>(text, bias, WT, P);
    k_bcast<<<2048, 256, 0, stream>>>(P, out);
}